// Round 1
// baseline (2069.425 us; speedup 1.0000x reference)
//
#include <hip/hip_runtime.h>
#include <hip/hip_bf16.h>

// Problem constants
#define TT   20
#define TS   19          // T-1 steps
#define BB   16
#define HH   128
#define WW   128
#define CINN 2
#define CHN  64
#define NOUT 10
#define BETA 0.9f
#define THRV 1.0f

#define FRAME_ELEMS (BB*HH*WW*CINN)          // 524288 floats per time slice
#define FLOW_ELEMS  (TS*FRAME_ELEMS)         // 9,961,472 floats
#define SPIKESUM_ELEMS (TS*BB*CHN)           // 19,456 floats
#define SPIKESUM_BYTES (SPIKESUM_ELEMS*4)    // 77,824 B (16B aligned)

// ---------------------------------------------------------------------------
// Kernel A: flow[i] = x[i + FRAME] - x[i], vectorized float4
// ---------------------------------------------------------------------------
__global__ __launch_bounds__(256) void flow_kernel(const float4* __restrict__ x,
                                                   float4* __restrict__ flow, int n4) {
    int i = blockIdx.x * 256 + threadIdx.x;
    if (i < n4) {
        float4 a = x[i];
        float4 b = x[i + FRAME_ELEMS / 4];
        float4 r;
        r.x = b.x - a.x; r.y = b.y - a.y; r.z = b.z - a.z; r.w = b.w - a.w;
        flow[i] = r;
    }
}

// ---------------------------------------------------------------------------
// Kernel B: fused conv + LIF scan.
// One wave = 64 lanes = 64 channels of 16 consecutive pixels in one row.
// Weights live in 18 per-lane VGPRs; flow window values are wave-uniform
// scalars (scalar loads). V[16] per lane persists across the t loop.
// ---------------------------------------------------------------------------
template <bool USE_FLOW>
__global__ __launch_bounds__(256) void lif_main(const float* __restrict__ x,
                                                const float* __restrict__ flow,
                                                const float* __restrict__ w_conv,
                                                const float* __restrict__ b_conv,
                                                float* __restrict__ spikesum) {
    const int lane = threadIdx.x & 63;
    const int wv   = __builtin_amdgcn_readfirstlane((int)(threadIdx.x >> 6)); // uniform wave id
    const int b    = blockIdx.y;
    const int y    = blockIdx.x >> 1;                 // row 0..127
    const int x0   = ((blockIdx.x & 1) << 6) + wv * 16; // 16-pixel segment base

    // per-lane (= per-channel) conv weights, loaded once
    float wreg[18];
#pragma unroll
    for (int k = 0; k < 18; ++k) wreg[k] = w_conv[k * CHN + lane];
    const float bc = b_conv[lane];

    float V[16];
#pragma unroll
    for (int p = 0; p < 16; ++p) V[p] = 0.f;

    const bool y0ok = (y > 0);
    const bool y2ok = (y < HH - 1);

    for (int t = 0; t < TS; ++t) {
        const float* fb;
        const float* fb1 = nullptr;
        if constexpr (USE_FLOW) {
            fb = flow + (size_t)(t * BB + b) * (HH * WW * CINN);
        } else {
            fb  = x + (size_t)(t * BB + b) * (HH * WW * CINN);
            fb1 = fb + (size_t)FRAME_ELEMS * BB / BB; // + one t-slice = BB*HH*WW*CINN? no:
        }
        if constexpr (!USE_FLOW) {
            // x layout [T][B][H][W][C]: next time slice is +B*H*W*C elements
            fb1 = fb + (size_t)BB * HH * WW * CINN;
        }

        float cnt = 0.f;
#pragma unroll
        for (int p = 0; p < 16; ++p) {
            const int xx = x0 + p;
            const bool xint = (xx > 0) && (xx < WW - 1);
            float f[18]; // wave-uniform window values (tap = (ky*3+kx)*2+ci)
#pragma unroll
            for (int r = 0; r < 3; ++r) {
                const int  yy  = y + r - 1;
                const bool rok = (r == 0) ? y0ok : ((r == 2) ? y2ok : true);
                if (rok && xint) {
                    const int rowoff = (yy * WW + xx - 1) * CINN;
                    if constexpr (USE_FLOW) {
#pragma unroll
                        for (int j = 0; j < 6; ++j) f[r * 6 + j] = fb[rowoff + j];
                    } else {
#pragma unroll
                        for (int j = 0; j < 6; ++j) f[r * 6 + j] = fb1[rowoff + j] - fb[rowoff + j];
                    }
                } else {
                    // boundary: clamp address (stay in-bounds), mask value
#pragma unroll
                    for (int j = 0; j < 6; ++j) {
                        const int  kx  = j >> 1;
                        const int  ci  = j & 1;
                        const int  col = xx - 1 + kx;
                        const bool ok  = rok && (col >= 0) && (col < WW);
                        const int  yyc = yy < 0 ? 0 : (yy > HH - 1 ? HH - 1 : yy);
                        const int  colc = col < 0 ? 0 : (col > WW - 1 ? WW - 1 : col);
                        const int  off = (yyc * WW + colc) * CINN + ci;
                        float v;
                        if constexpr (USE_FLOW) v = fb[off];
                        else                    v = fb1[off] - fb[off];
                        f[r * 6 + j] = ok ? v : 0.f;
                    }
                }
            }
            float u = bc;
#pragma unroll
            for (int k = 0; k < 18; ++k) u = fmaf(f[k], wreg[k], u);
            float v  = fmaf(BETA, V[p], u);
            bool  sp = v > THRV;
            cnt += sp ? 1.f : 0.f;
            V[p] = sp ? (v - THRV) : v;
        }
        atomicAdd(&spikesum[(t * BB + b) * CHN + lane], cnt);
    }
}

// ---------------------------------------------------------------------------
// Kernel C: logits[t][b][o] = (spikesum[t][b][:]/16384) @ w_head + b_head
// one 64-thread block per (t,b); thread = channel; wave-shuffle reduce.
// ---------------------------------------------------------------------------
__global__ __launch_bounds__(64) void logits_kernel(const float* __restrict__ spikesum,
                                                    const float* __restrict__ w_head,
                                                    const float* __restrict__ b_head,
                                                    float* __restrict__ out) {
    const int t = blockIdx.x, b = blockIdx.y, ch = threadIdx.x;
    const float s = spikesum[(t * BB + b) * CHN + ch] * (1.f / (HH * WW));
    float acc[NOUT];
#pragma unroll
    for (int o = 0; o < NOUT; ++o) acc[o] = s * w_head[ch * NOUT + o];
#pragma unroll
    for (int off = 32; off > 0; off >>= 1) {
#pragma unroll
        for (int o = 0; o < NOUT; ++o) acc[o] += __shfl_down(acc[o], off);
    }
    if (ch == 0) {
#pragma unroll
        for (int o = 0; o < NOUT; ++o)
            out[BB * NOUT + (t * BB + b) * NOUT + o] = acc[o] + b_head[o];
    }
}

// ---------------------------------------------------------------------------
// Kernel D: readout = mean_t(logits); sr = total spikes / (TS*B*H*W*CH)
// single block of 256 threads.
// ---------------------------------------------------------------------------
__global__ __launch_bounds__(256) void final_kernel(const float* __restrict__ spikesum,
                                                    float* __restrict__ out) {
    const int tid = threadIdx.x;
    const float* logits = out + BB * NOUT;
    if (tid < BB * NOUT) {
        const int b = tid / NOUT, o = tid % NOUT;
        float a = 0.f;
#pragma unroll
        for (int t = 0; t < TS; ++t) a += logits[(t * BB + b) * NOUT + o];
        out[tid] = a * (1.f / TS);
    }
    float s = 0.f;
    for (int i = tid; i < SPIKESUM_ELEMS; i += 256) s += spikesum[i];
#pragma unroll
    for (int off = 32; off > 0; off >>= 1) s += __shfl_down(s, off);
    __shared__ float red[4];
    if ((tid & 63) == 0) red[tid >> 6] = s;
    __syncthreads();
    if (tid == 0)
        out[BB * NOUT + TS * BB * NOUT] =
            (red[0] + red[1] + red[2] + red[3]) * (1.f / ((float)TS * BB * HH * WW * CHN));
}

// ---------------------------------------------------------------------------
extern "C" void kernel_launch(void* const* d_in, const int* in_sizes, int n_in,
                              void* d_out, int out_size, void* d_ws, size_t ws_size,
                              hipStream_t stream) {
    (void)in_sizes; (void)n_in; (void)out_size;
    const float* x      = (const float*)d_in[0];
    const float* w_conv = (const float*)d_in[1];
    const float* b_conv = (const float*)d_in[2];
    const float* w_head = (const float*)d_in[3];
    const float* b_head = (const float*)d_in[4];
    float* out      = (float*)d_out;
    float* spikesum = (float*)d_ws;

    const size_t FLOW_OFF   = SPIKESUM_BYTES;            // 16B-aligned
    const size_t FLOW_BYTES = (size_t)FLOW_ELEMS * 4;
    const bool   use_flow   = ws_size >= FLOW_OFF + FLOW_BYTES;

    hipMemsetAsync(d_ws, 0, SPIKESUM_BYTES, stream);

    if (use_flow) {
        float* flow = (float*)((char*)d_ws + FLOW_OFF);
        const int n4 = FLOW_ELEMS / 4;
        flow_kernel<<<(n4 + 255) / 256, 256, 0, stream>>>((const float4*)x, (float4*)flow, n4);
        lif_main<true><<<dim3(HH * WW / 64, BB), 256, 0, stream>>>(x, flow, w_conv, b_conv, spikesum);
    } else {
        lif_main<false><<<dim3(HH * WW / 64, BB), 256, 0, stream>>>(x, nullptr, w_conv, b_conv, spikesum);
    }

    logits_kernel<<<dim3(TS, BB), 64, 0, stream>>>(spikesum, w_head, b_head, out);
    final_kernel<<<1, 256, 0, stream>>>(spikesum, out);
}

// Round 3
// 480.453 us; speedup vs baseline: 4.3072x; 4.3072x over previous
//
#include <hip/hip_runtime.h>
#include <hip/hip_bf16.h>

// Problem constants
#define TT   20
#define TS   19          // T-1 steps
#define BB   16
#define HH   128
#define WW   128
#define CINN 2
#define CHN  64
#define NOUT 10
#define BETA 0.9f
#define THRV 1.0f

#define FRAME_ELEMS (BB*HH*WW*CINN)          // 524288 floats per time slice
#define FLOW_ELEMS  (TS*FRAME_ELEMS)         // 9,961,472 floats
#define SPIKESUM_ELEMS (TS*BB*CHN)           // 19,456 ints
#define SPIKESUM_BYTES (SPIKESUM_ELEMS*4)    // 77,824 B
#define WPACK_OFF   SPIKESUM_BYTES           // 64*20 floats = 5120 B
#define WPACK_ELEMS (CHN*20)
#define FLOW_OFF    (WPACK_OFF + WPACK_ELEMS*4)   // 82,944 (16B aligned)

// ---------------------------------------------------------------------------
// Kernel A: flow = x[t+1]-x[t] (float4), plus weight repack in block 0.
// wpack[ch*20 + k] = w_conv[k*64 + ch] for k=0..17; [18]=bias; [19]=0
// ---------------------------------------------------------------------------
__global__ __launch_bounds__(256) void flow_kernel(const float4* __restrict__ x,
                                                   const float* __restrict__ w_conv,
                                                   const float* __restrict__ b_conv,
                                                   float4* __restrict__ flow,
                                                   float* __restrict__ wpack, int n4) {
    int i = blockIdx.x * 256 + threadIdx.x;
    if (i < n4) {
        float4 a = x[i];
        float4 b = x[i + FRAME_ELEMS / 4];
        float4 r;
        r.x = b.x - a.x; r.y = b.y - a.y; r.z = b.z - a.z; r.w = b.w - a.w;
        flow[i] = r;
    }
    if (blockIdx.x == 0 && threadIdx.x < CHN) {
        const int ch = threadIdx.x;
#pragma unroll
        for (int k = 0; k < 18; ++k) wpack[ch * 20 + k] = w_conv[k * CHN + ch];
        wpack[ch * 20 + 18] = b_conv[ch];
        wpack[ch * 20 + 19] = 0.f;
    }
}

// ---------------------------------------------------------------------------
// Kernel B: fused conv + LIF scan, lane = pixel, channel = inner loop.
// One wave = 64 consecutive pixels of one row; V[64 channels] per lane in
// VGPRs across the whole t-loop. Weights are wave-uniform scalar loads.
// Spike counts per (t,ch): ballot + popcount (wave-uniform), lane==ch keeps
// its channel's count via cndmask; one vector atomicAdd per wave per t.
// Grid: (HH/2, BB) blocks x 256 threads; wave wv handles row 2*bx+(wv>>1),
// pixel half (wv&1).
// ---------------------------------------------------------------------------
__global__ __launch_bounds__(256, 4) void lif_main(const float* __restrict__ flow,
                                                   const float* __restrict__ wpk,
                                                   int* __restrict__ spikesum) {
    const int lane = threadIdx.x & 63;
    const int wv   = __builtin_amdgcn_readfirstlane((int)(threadIdx.x >> 6));
    const int b    = blockIdx.y;
    const int row  = (blockIdx.x << 1) + (wv >> 1);   // uniform
    const int xx   = ((wv & 1) << 6) + lane;          // per-lane pixel x

    // loop-invariant per-lane column indices (float2 units) + edge masks
    const int  c0 = (xx > 0)  ? (xx - 1) : 0;
    const int  c2 = (xx < WW - 1) ? (xx + 1) : (WW - 1);
    const bool m0 = (xx > 0);
    const bool m2 = (xx < WW - 1);

    float V[CHN];
#pragma unroll
    for (int ch = 0; ch < CHN; ++ch) V[ch] = 0.f;

    for (int t = 0; t < TS; ++t) {
        float f[18];
#pragma unroll
        for (int r = 0; r < 3; ++r) {
            const int yy = row + r - 1;               // uniform
            if (yy >= 0 && yy <= HH - 1) {            // uniform branch
                const float2* rowp =
                    (const float2*)(flow + ((size_t)((t * BB + b) * HH + yy)) * (WW * CINN));
                float2 a = rowp[c0];
                float2 m = rowp[xx];
                float2 c = rowp[c2];
                f[r * 6 + 0] = m0 ? a.x : 0.f;
                f[r * 6 + 1] = m0 ? a.y : 0.f;
                f[r * 6 + 2] = m.x;
                f[r * 6 + 3] = m.y;
                f[r * 6 + 4] = m2 ? c.x : 0.f;
                f[r * 6 + 5] = m2 ? c.y : 0.f;
            } else {
#pragma unroll
                for (int j = 0; j < 6; ++j) f[r * 6 + j] = 0.f;
            }
        }

        int cnt_v = 0;
#pragma unroll
        for (int ch = 0; ch < CHN; ++ch) {
            const float* wp = wpk + ch * 20;          // uniform -> s_load
            float u = wp[18];
#pragma unroll
            for (int k = 0; k < 18; ++k) u = fmaf(f[k], wp[k], u);
            float v  = fmaf(BETA, V[ch], u);
            bool  sp = v > THRV;
            V[ch]    = sp ? (v - THRV) : v;
            unsigned long long mb = __ballot(sp);     // wave-uniform mask
            int popc = (int)__popcll(mb);             // wave-uniform count
            cnt_v = (lane == ch) ? popc : cnt_v;      // lane ch keeps channel ch
        }
        atomicAdd(&spikesum[(t * BB + b) * CHN + lane], cnt_v);
    }
}

// ---------------------------------------------------------------------------
// Kernel C: logits[t][b][o] = (spikesum[t][b][:]/16384) @ w_head + b_head
// ---------------------------------------------------------------------------
__global__ __launch_bounds__(64) void logits_kernel(const int* __restrict__ spikesum,
                                                    const float* __restrict__ w_head,
                                                    const float* __restrict__ b_head,
                                                    float* __restrict__ out) {
    const int t = blockIdx.x, b = blockIdx.y, ch = threadIdx.x;
    const float s = (float)spikesum[(t * BB + b) * CHN + ch] * (1.f / (HH * WW));
    float acc[NOUT];
#pragma unroll
    for (int o = 0; o < NOUT; ++o) acc[o] = s * w_head[ch * NOUT + o];
#pragma unroll
    for (int off = 32; off > 0; off >>= 1) {
#pragma unroll
        for (int o = 0; o < NOUT; ++o) acc[o] += __shfl_down(acc[o], off);
    }
    if (ch == 0) {
#pragma unroll
        for (int o = 0; o < NOUT; ++o)
            out[BB * NOUT + (t * BB + b) * NOUT + o] = acc[o] + b_head[o];
    }
}

// ---------------------------------------------------------------------------
// Kernel D: readout = mean_t(logits); sr = total spikes / (TS*B*H*W*CH)
// ---------------------------------------------------------------------------
__global__ __launch_bounds__(256) void final_kernel(const int* __restrict__ spikesum,
                                                    float* __restrict__ out) {
    const int tid = threadIdx.x;
    const float* logits = out + BB * NOUT;
    if (tid < BB * NOUT) {
        const int b = tid / NOUT, o = tid % NOUT;
        float a = 0.f;
#pragma unroll
        for (int t = 0; t < TS; ++t) a += logits[(t * BB + b) * NOUT + o];
        out[tid] = a * (1.f / TS);
    }
    int s = 0;
    for (int i = tid; i < SPIKESUM_ELEMS; i += 256) s += spikesum[i];
#pragma unroll
    for (int off = 32; off > 0; off >>= 1) s += __shfl_down(s, off);
    __shared__ int red[4];
    if ((tid & 63) == 0) red[tid >> 6] = s;
    __syncthreads();
    if (tid == 0)
        out[BB * NOUT + TS * BB * NOUT] =
            (float)(red[0] + red[1] + red[2] + red[3]) *
            (1.f / ((float)TS * BB * HH * WW * CHN));
}

// ---------------------------------------------------------------------------
extern "C" void kernel_launch(void* const* d_in, const int* in_sizes, int n_in,
                              void* d_out, int out_size, void* d_ws, size_t ws_size,
                              hipStream_t stream) {
    (void)in_sizes; (void)n_in; (void)out_size; (void)ws_size;
    const float* x      = (const float*)d_in[0];
    const float* w_conv = (const float*)d_in[1];
    const float* b_conv = (const float*)d_in[2];
    const float* w_head = (const float*)d_in[3];
    const float* b_head = (const float*)d_in[4];
    float* out      = (float*)d_out;
    int*   spikesum = (int*)d_ws;
    float* wpack    = (float*)((char*)d_ws + WPACK_OFF);
    float* flow     = (float*)((char*)d_ws + FLOW_OFF);

    (void)hipMemsetAsync(d_ws, 0, SPIKESUM_BYTES, stream);

    const int n4 = FLOW_ELEMS / 4;
    flow_kernel<<<(n4 + 255) / 256, 256, 0, stream>>>((const float4*)x, w_conv, b_conv,
                                                      (float4*)flow, wpack, n4);
    lif_main<<<dim3(HH / 2, BB), 256, 0, stream>>>(flow, wpack, spikesum);
    logits_kernel<<<dim3(TS, BB), 64, 0, stream>>>(spikesum, w_head, b_head, out);
    final_kernel<<<1, 256, 0, stream>>>(spikesum, out);
}

// Round 4
// 435.333 us; speedup vs baseline: 4.7537x; 1.1036x over previous
//
#include <hip/hip_runtime.h>
#include <hip/hip_bf16.h>

// Problem constants
#define TT   20
#define TS   19          // T-1 steps
#define BB   16
#define HH   128
#define WW   128
#define CINN 2
#define CHN  64
#define NOUT 10
#define BETA 0.9f
#define THRV 1.0f

#define FRAME_ELEMS (BB*HH*WW*CINN)          // 524288 floats per time slice
#define FLOW_ELEMS  (TS*FRAME_ELEMS)         // 9,961,472 floats
#define SPIKESUM_ELEMS (TS*BB*CHN)           // 19,456 ints
#define SPIKESUM_BYTES (SPIKESUM_ELEMS*4)    // 77,824 B
#define WPACK_OFF   SPIKESUM_BYTES           // 64*20 floats = 5120 B
#define WPACK_ELEMS (CHN*20)
#define FLOW_OFF    (WPACK_OFF + WPACK_ELEMS*4)   // 82,944 (16B aligned)

// ---------------------------------------------------------------------------
// Kernel A: flow = x[t+1]-x[t] (float4), plus weight repack in block 0.
// wpack[ch*20 + k] = w_conv[k*64 + ch] for k=0..17; [18]=bias; [19]=0
// ---------------------------------------------------------------------------
__global__ __launch_bounds__(256) void flow_kernel(const float4* __restrict__ x,
                                                   const float* __restrict__ w_conv,
                                                   const float* __restrict__ b_conv,
                                                   float4* __restrict__ flow,
                                                   float* __restrict__ wpack, int n4) {
    int i = blockIdx.x * 256 + threadIdx.x;
    if (i < n4) {
        float4 a = x[i];
        float4 b = x[i + FRAME_ELEMS / 4];
        float4 r;
        r.x = b.x - a.x; r.y = b.y - a.y; r.z = b.z - a.z; r.w = b.w - a.w;
        flow[i] = r;
    }
    if (blockIdx.x == 0 && threadIdx.x < CHN) {
        const int ch = threadIdx.x;
#pragma unroll
        for (int k = 0; k < 18; ++k) wpack[ch * 20 + k] = w_conv[k * CHN + ch];
        wpack[ch * 20 + 18] = b_conv[ch];
        wpack[ch * 20 + 19] = 0.f;
    }
}

// ---------------------------------------------------------------------------
// Kernel B: fused conv + LIF scan.
// lane = pixel (64 consecutive pixels = half row), wave owns 16 channels
// (V[16] per lane in VGPRs — small enough for SROA promotion, unlike V[64]
// which spilled to scratch in R3). 4 chunk-waves cover the 64 channels.
// Weights are wave-uniform scalar loads. Spike counts per (t,ch): ballot +
// popcount (wave-uniform), lane c keeps chunk-local channel c's count;
// lanes 0..15 do one atomicAdd per wave per t.
// Grid: (HH, BB, 2) x 256 threads; wave wv: half = wv&1,
// chunk = blockIdx.z*2 + (wv>>1).
// ---------------------------------------------------------------------------
__global__ __launch_bounds__(256, 4) void lif_main(const float* __restrict__ flow,
                                                   const float* __restrict__ wpk,
                                                   int* __restrict__ spikesum) {
    const int lane  = threadIdx.x & 63;
    const int wv    = __builtin_amdgcn_readfirstlane((int)(threadIdx.x >> 6));
    const int b     = blockIdx.y;
    const int row   = blockIdx.x;                       // uniform 0..127
    const int chunk = (blockIdx.z << 1) | (wv >> 1);    // uniform 0..3
    const int base_ch = chunk << 4;
    const int xx    = ((wv & 1) << 6) + lane;           // per-lane pixel x

    // loop-invariant per-lane column indices (float2 units) + edge masks
    const int  c0 = (xx > 0)  ? (xx - 1) : 0;
    const int  c2 = (xx < WW - 1) ? (xx + 1) : (WW - 1);
    const bool m0 = (xx > 0);
    const bool m2 = (xx < WW - 1);

    float V[16];
#pragma unroll
    for (int i = 0; i < 16; ++i) V[i] = 0.f;

    const bool do_atomic = (lane < 16);

    for (int t = 0; t < TS; ++t) {
        float f[18];
#pragma unroll
        for (int r = 0; r < 3; ++r) {
            const int yy = row + r - 1;                 // uniform
            if (yy >= 0 && yy <= HH - 1) {              // uniform branch
                const float2* rowp =
                    (const float2*)(flow + ((size_t)((t * BB + b) * HH + yy)) * (WW * CINN));
                float2 a = rowp[c0];
                float2 m = rowp[xx];
                float2 c = rowp[c2];
                f[r * 6 + 0] = m0 ? a.x : 0.f;
                f[r * 6 + 1] = m0 ? a.y : 0.f;
                f[r * 6 + 2] = m.x;
                f[r * 6 + 3] = m.y;
                f[r * 6 + 4] = m2 ? c.x : 0.f;
                f[r * 6 + 5] = m2 ? c.y : 0.f;
            } else {
#pragma unroll
                for (int j = 0; j < 6; ++j) f[r * 6 + j] = 0.f;
            }
        }

        int cnt_v = 0;
#pragma unroll
        for (int c = 0; c < 16; ++c) {
            const float* wp = wpk + (base_ch + c) * 20; // uniform -> s_load
            float u = wp[18];
#pragma unroll
            for (int k = 0; k < 18; ++k) u = fmaf(f[k], wp[k], u);
            float v  = fmaf(BETA, V[c], u);
            bool  sp = v > THRV;
            V[c]     = sp ? (v - THRV) : v;
            unsigned long long mb = __ballot(sp);       // wave-uniform mask
            int popc = (int)__popcll(mb);               // wave-uniform count
            cnt_v = (lane == c) ? popc : cnt_v;         // lane c keeps local ch c
        }
        if (do_atomic)
            atomicAdd(&spikesum[(t * BB + b) * CHN + base_ch + lane], cnt_v);
    }
}

// ---------------------------------------------------------------------------
// Kernel C: logits[t][b][o] = (spikesum[t][b][:]/16384) @ w_head + b_head
// ---------------------------------------------------------------------------
__global__ __launch_bounds__(64) void logits_kernel(const int* __restrict__ spikesum,
                                                    const float* __restrict__ w_head,
                                                    const float* __restrict__ b_head,
                                                    float* __restrict__ out) {
    const int t = blockIdx.x, b = blockIdx.y, ch = threadIdx.x;
    const float s = (float)spikesum[(t * BB + b) * CHN + ch] * (1.f / (HH * WW));
    float acc[NOUT];
#pragma unroll
    for (int o = 0; o < NOUT; ++o) acc[o] = s * w_head[ch * NOUT + o];
#pragma unroll
    for (int off = 32; off > 0; off >>= 1) {
#pragma unroll
        for (int o = 0; o < NOUT; ++o) acc[o] += __shfl_down(acc[o], off);
    }
    if (ch == 0) {
#pragma unroll
        for (int o = 0; o < NOUT; ++o)
            out[BB * NOUT + (t * BB + b) * NOUT + o] = acc[o] + b_head[o];
    }
}

// ---------------------------------------------------------------------------
// Kernel D: readout = mean_t(logits); sr = total spikes / (TS*B*H*W*CH)
// ---------------------------------------------------------------------------
__global__ __launch_bounds__(256) void final_kernel(const int* __restrict__ spikesum,
                                                    float* __restrict__ out) {
    const int tid = threadIdx.x;
    const float* logits = out + BB * NOUT;
    if (tid < BB * NOUT) {
        const int b = tid / NOUT, o = tid % NOUT;
        float a = 0.f;
#pragma unroll
        for (int t = 0; t < TS; ++t) a += logits[(t * BB + b) * NOUT + o];
        out[tid] = a * (1.f / TS);
    }
    int s = 0;
    for (int i = tid; i < SPIKESUM_ELEMS; i += 256) s += spikesum[i];
#pragma unroll
    for (int off = 32; off > 0; off >>= 1) s += __shfl_down(s, off);
    __shared__ int red[4];
    if ((tid & 63) == 0) red[tid >> 6] = s;
    __syncthreads();
    if (tid == 0)
        out[BB * NOUT + TS * BB * NOUT] =
            (float)(red[0] + red[1] + red[2] + red[3]) *
            (1.f / ((float)TS * BB * HH * WW * CHN));
}

// ---------------------------------------------------------------------------
extern "C" void kernel_launch(void* const* d_in, const int* in_sizes, int n_in,
                              void* d_out, int out_size, void* d_ws, size_t ws_size,
                              hipStream_t stream) {
    (void)in_sizes; (void)n_in; (void)out_size; (void)ws_size;
    const float* x      = (const float*)d_in[0];
    const float* w_conv = (const float*)d_in[1];
    const float* b_conv = (const float*)d_in[2];
    const float* w_head = (const float*)d_in[3];
    const float* b_head = (const float*)d_in[4];
    float* out      = (float*)d_out;
    int*   spikesum = (int*)d_ws;
    float* wpack    = (float*)((char*)d_ws + WPACK_OFF);
    float* flow     = (float*)((char*)d_ws + FLOW_OFF);

    (void)hipMemsetAsync(d_ws, 0, SPIKESUM_BYTES, stream);

    const int n4 = FLOW_ELEMS / 4;
    flow_kernel<<<(n4 + 255) / 256, 256, 0, stream>>>((const float4*)x, w_conv, b_conv,
                                                      (float4*)flow, wpack, n4);
    lif_main<<<dim3(HH, BB, 2), 256, 0, stream>>>(flow, wpack, spikesum);
    logits_kernel<<<dim3(TS, BB), 64, 0, stream>>>(spikesum, w_head, b_head, out);
    final_kernel<<<1, 256, 0, stream>>>(spikesum, out);
}

// Round 5
// 335.761 us; speedup vs baseline: 6.1634x; 1.2966x over previous
//
#include <hip/hip_runtime.h>
#include <hip/hip_bf16.h>

// Problem constants
#define TT   20
#define TS   19          // T-1 steps
#define BB   16
#define HH   128
#define WW   128
#define CINN 2
#define CHN  64
#define NOUT 10
#define BETA 0.9f
#define THRV 1.0f

#define FRAME_ELEMS (BB*HH*WW*CINN)          // 524288 floats per time slice
#define SPIKESUM_ELEMS (TS*BB*CHN)           // 19,456 ints
#define SPIKESUM_BYTES (SPIKESUM_ELEMS*4)    // 77,824 B

typedef __attribute__((ext_vector_type(8))) short short8;
typedef __attribute__((ext_vector_type(4))) float float4v;
typedef __attribute__((ext_vector_type(4))) int   int4v;

// round-to-nearest-even fp32 -> bf16 bits
__device__ __forceinline__ unsigned rne16(float f) {
    unsigned u = __float_as_uint(f);
    return (u + 0x7fffu + ((u >> 16) & 1u)) >> 16;
}
__device__ __forceinline__ float b2f(unsigned us) {
    return __uint_as_float(us << 16);
}

// ---------------------------------------------------------------------------
// Fused flow-diff + 3x3 conv (bf16-split MFMA) + LIF scan + spike count.
//
// Block = 64 pixels of one row (4 waves x 16 px), all 64 channels.
// Per t: stage 3 rows x 68 px x 2ci of (x[t+1]-x[t]) into LDS as packed
// (hi16|lo16) bf16-split dwords; each wave builds A-fragments
// (A[m=lane&15][k=quad*8+j], k-remap: quad=ky, j=kx*2+ci, j=6,7 & quad=3
// zero-padded) with ds_read_b64 x3; weights live in B-fragments
// (B[k][n=lane&15]) built once before the t-loop. Conv u = bias + Ah*Bh +
// Al*Bh + Ah*Bl (drops only Alo*Blo ~ 2^-16 relative). LIF on the C/D
// fragment (row = quad*4+reg = pixel, col = lane&15 = channel within group);
// spike counts reduced via shfl_xor(16,32), one 64-lane atomicAdd (lane=ch).
// ---------------------------------------------------------------------------
__global__ __launch_bounds__(256, 4) void lif_main(const float* __restrict__ x,
                                                   const float* __restrict__ w_conv,
                                                   const float* __restrict__ b_conv,
                                                   int* __restrict__ spikesum) {
    __shared__ unsigned ldsbuf[3 * 144];     // 3 rows x (136 scalars + 8 pad) dwords

    const int tid  = threadIdx.x;
    const int lane = tid & 63;
    const int wv   = __builtin_amdgcn_readfirstlane(tid >> 6); // uniform wave id 0..3
    const int bx   = blockIdx.x;             // 0..1 : pixel half of the row
    const int by   = blockIdx.y;             // 0..127 : row
    const int bz   = blockIdx.z;             // 0..15 : batch
    const int x0   = bx << 6;                // 64-pixel segment base
    const int q    = lane >> 4;              // quad (ky for A/B, pixel-group for C/D)
    const int col  = lane & 15;              // n (channel-in-group) for B/C/D; m (pixel) for A

    // ---- B fragments (weights), built once: k = q*8+j ; j<6: kx=j>>1, ci=j&1
    short8 Bh[4], Bl[4];
    float  biasv[4];
#pragma unroll
    for (int cg = 0; cg < 4; ++cg) {
        int hi_i[4] = {0, 0, 0, 0}, lo_i[4] = {0, 0, 0, 0};
#pragma unroll
        for (int j = 0; j < 6; ++j) {
            float w = 0.f;
            if (q < 3)
                w = w_conv[((q * 3 + (j >> 1)) * 2 + (j & 1)) * CHN + cg * 16 + col];
            unsigned hs = rne16(w);
            unsigned ls = rne16(w - b2f(hs));
            hi_i[j >> 1] |= (int)(hs << (16 * (j & 1)));
            lo_i[j >> 1] |= (int)(ls << (16 * (j & 1)));
        }
        int4v hv = {hi_i[0], hi_i[1], hi_i[2], hi_i[3]};
        int4v lv = {lo_i[0], lo_i[1], lo_i[2], lo_i[3]};
        Bh[cg] = __builtin_bit_cast(short8, hv);
        Bl[cg] = __builtin_bit_cast(short8, lv);
        biasv[cg] = b_conv[cg * 16 + col];
    }

    float V[4][4];
#pragma unroll
    for (int cg = 0; cg < 4; ++cg)
#pragma unroll
        for (int r = 0; r < 4; ++r) V[cg][r] = 0.f;

    // A-fragment LDS base (dwords): row q, scalar start (wv*16 + m + 1)*2
    const int abase = q * 144 + ((wv << 4) + col + 1) * 2;

    for (int t = 0; t < TS; ++t) {
        // ---- stage (x[t+1]-x[t]) split into (hi|lo<<16) packed dwords
        const size_t slice = (size_t)(t * BB + bz) * (HH * WW * CINN);
#pragma unroll
        for (int it = 0; it < 2; ++it) {
            int i = tid + it * 256;
            if (i < 408) {
                int r = i / 136;
                int s = i - r * 136;
                int y  = by + r - 1;
                int px = x0 - 2 + (s >> 1);
                unsigned v = 0;
                if ((unsigned)y < (unsigned)HH && (unsigned)px < (unsigned)WW) {
                    size_t idx = slice + ((size_t)(y * WW + px) << 1) + (s & 1);
                    float d = x[idx + FRAME_ELEMS] - x[idx];
                    unsigned hs = rne16(d);
                    unsigned ls = rne16(d - b2f(hs));
                    v = hs | (ls << 16);
                }
                ldsbuf[r * 144 + s] = v;
            }
        }
        __syncthreads();

        // ---- A fragments (6 contiguous dwords; quad 3 and j=6,7 are zero)
        unsigned d0 = 0, d1 = 0, d2 = 0, d3 = 0, d4 = 0, d5 = 0;
        if (q < 3) {
            const unsigned* Lp = &ldsbuf[abase];
            d0 = Lp[0]; d1 = Lp[1]; d2 = Lp[2]; d3 = Lp[3]; d4 = Lp[4]; d5 = Lp[5];
        }
        __syncthreads();  // reads done before next iteration's staging

        int4v ah = {(int)((d0 & 0xffffu) | (d1 << 16)),
                    (int)((d2 & 0xffffu) | (d3 << 16)),
                    (int)((d4 & 0xffffu) | (d5 << 16)), 0};
        int4v al = {(int)((d0 >> 16) | (d1 & 0xffff0000u)),
                    (int)((d2 >> 16) | (d3 & 0xffff0000u)),
                    (int)((d4 >> 16) | (d5 & 0xffff0000u)), 0};
        short8 Ah = __builtin_bit_cast(short8, ah);
        short8 Al = __builtin_bit_cast(short8, al);

        // ---- conv (MFMA) + LIF + count
        int cnt[4];
#pragma unroll
        for (int cg = 0; cg < 4; ++cg) {
            float4v u = {biasv[cg], biasv[cg], biasv[cg], biasv[cg]};
            u = __builtin_amdgcn_mfma_f32_16x16x32_bf16(Ah, Bh[cg], u, 0, 0, 0);
            u = __builtin_amdgcn_mfma_f32_16x16x32_bf16(Al, Bh[cg], u, 0, 0, 0);
            u = __builtin_amdgcn_mfma_f32_16x16x32_bf16(Ah, Bl[cg], u, 0, 0, 0);
            int c = 0;
#pragma unroll
            for (int r = 0; r < 4; ++r) {
                float v  = fmaf(BETA, V[cg][r], u[r]);
                bool  sp = v > THRV;
                c += sp ? 1 : 0;
                V[cg][r] = sp ? (v - THRV) : v;
            }
            c += __shfl_xor(c, 16);
            c += __shfl_xor(c, 32);
            cnt[cg] = c;
        }
        int my = (q == 0) ? cnt[0] : (q == 1) ? cnt[1] : (q == 2) ? cnt[2] : cnt[3];
        // channel = q*16 + col = lane
        atomicAdd(&spikesum[(t * BB + bz) * CHN + lane], my);
    }
}

// ---------------------------------------------------------------------------
// logits[t][b][o] = (spikesum[t][b][:]/16384) @ w_head + b_head
// ---------------------------------------------------------------------------
__global__ __launch_bounds__(64) void logits_kernel(const int* __restrict__ spikesum,
                                                    const float* __restrict__ w_head,
                                                    const float* __restrict__ b_head,
                                                    float* __restrict__ out) {
    const int t = blockIdx.x, b = blockIdx.y, ch = threadIdx.x;
    const float s = (float)spikesum[(t * BB + b) * CHN + ch] * (1.f / (HH * WW));
    float acc[NOUT];
#pragma unroll
    for (int o = 0; o < NOUT; ++o) acc[o] = s * w_head[ch * NOUT + o];
#pragma unroll
    for (int off = 32; off > 0; off >>= 1) {
#pragma unroll
        for (int o = 0; o < NOUT; ++o) acc[o] += __shfl_down(acc[o], off);
    }
    if (ch == 0) {
#pragma unroll
        for (int o = 0; o < NOUT; ++o)
            out[BB * NOUT + (t * BB + b) * NOUT + o] = acc[o] + b_head[o];
    }
}

// ---------------------------------------------------------------------------
// readout = mean_t(logits); sr = total spikes / (TS*B*H*W*CH)
// ---------------------------------------------------------------------------
__global__ __launch_bounds__(256) void final_kernel(const int* __restrict__ spikesum,
                                                    float* __restrict__ out) {
    const int tid = threadIdx.x;
    const float* logits = out + BB * NOUT;
    if (tid < BB * NOUT) {
        const int b = tid / NOUT, o = tid % NOUT;
        float a = 0.f;
#pragma unroll
        for (int t = 0; t < TS; ++t) a += logits[(t * BB + b) * NOUT + o];
        out[tid] = a * (1.f / TS);
    }
    int s = 0;
    for (int i = tid; i < SPIKESUM_ELEMS; i += 256) s += spikesum[i];
#pragma unroll
    for (int off = 32; off > 0; off >>= 1) s += __shfl_down(s, off);
    __shared__ int red[4];
    if ((tid & 63) == 0) red[tid >> 6] = s;
    __syncthreads();
    if (tid == 0)
        out[BB * NOUT + TS * BB * NOUT] =
            (float)(red[0] + red[1] + red[2] + red[3]) *
            (1.f / ((float)TS * BB * HH * WW * CHN));
}

// ---------------------------------------------------------------------------
extern "C" void kernel_launch(void* const* d_in, const int* in_sizes, int n_in,
                              void* d_out, int out_size, void* d_ws, size_t ws_size,
                              hipStream_t stream) {
    (void)in_sizes; (void)n_in; (void)out_size; (void)ws_size;
    const float* x      = (const float*)d_in[0];
    const float* w_conv = (const float*)d_in[1];
    const float* b_conv = (const float*)d_in[2];
    const float* w_head = (const float*)d_in[3];
    const float* b_head = (const float*)d_in[4];
    float* out      = (float*)d_out;
    int*   spikesum = (int*)d_ws;

    (void)hipMemsetAsync(d_ws, 0, SPIKESUM_BYTES, stream);

    lif_main<<<dim3(2, HH, BB), 256, 0, stream>>>(x, w_conv, b_conv, spikesum);
    logits_kernel<<<dim3(TS, BB), 64, 0, stream>>>(spikesum, w_head, b_head, out);
    final_kernel<<<1, 256, 0, stream>>>(spikesum, out);
}

// Round 6
// 208.052 us; speedup vs baseline: 9.9467x; 1.6138x over previous
//
#include <hip/hip_runtime.h>
#include <hip/hip_bf16.h>

// Problem constants
#define TT   20
#define TS   19          // T-1 steps
#define BB   16
#define HH   128
#define WW   128
#define CINN 2
#define CHN  64
#define NOUT 10
#define BETA 0.9f
#define THRV 1.0f

#define FRAME_ELEMS (BB*HH*WW*CINN)          // 524288 floats per time slice
#define SPIKESUM_ELEMS (TS*BB*CHN)           // 19,456 ints
#define SPIKESUM_BYTES (SPIKESUM_ELEMS*4)    // 77,824 B

#define LROW   136                            // dwords per LDS row (132 used + 4 pad)
#define NSTG   528                            // 4 rows x 132 dwords staged per t

typedef __attribute__((ext_vector_type(8))) short short8;
typedef __attribute__((ext_vector_type(4))) float float4v;
typedef __attribute__((ext_vector_type(4))) int   int4v;

// round-to-nearest-even fp32 -> bf16 bits
__device__ __forceinline__ unsigned rne16(float f) {
    unsigned u = __float_as_uint(f);
    return (u + 0x7fffu + ((u >> 16) & 1u)) >> 16;
}
__device__ __forceinline__ float b2f(unsigned us) {
    return __uint_as_float(us << 16);
}

// ---------------------------------------------------------------------------
// Fused flow-diff + 3x3 conv (bf16-split MFMA) + LIF scan + spike count.
//
// Block = 2 rows x 64 px, all 64 channels. Wave w owns 16 px (both rows,
// 2 A-fragment sets). Software-pipelined t-loop, double-buffered LDS,
// ONE barrier per t:
//   pack(raw[t]) -> p ; ds_write p -> buf[t&1] ; barrier ;
//   issue raw loads[t+1] (overlap) ; ds_read A ; 24 MFMA ; LIF ; atomic
// Staging addresses/validity are t-invariant (precomputed).
// u = bias + Ah*Bh + Al*Bh + Ah*Bl (drops Alo*Blo ~ 2^-16 relative).
// C/D layout: row(pixel) = q*4+reg, col(channel-in-group) = lane&15.
// ---------------------------------------------------------------------------
__global__ __launch_bounds__(256, 4) void lif_main(const float* __restrict__ x,
                                                   const float* __restrict__ w_conv,
                                                   const float* __restrict__ b_conv,
                                                   int* __restrict__ spikesum) {
    __shared__ unsigned lds2[2][4 * LROW];   // 2 x 544 dwords = 4352 B

    const int tid  = threadIdx.x;
    const int lane = tid & 63;
    const int wv   = __builtin_amdgcn_readfirstlane(tid >> 6); // uniform 0..3
    const int bx   = blockIdx.x;             // 0..1 : pixel half
    const int r0   = blockIdx.y << 1;        // first of 2 output rows
    const int bz   = blockIdx.z;             // batch
    const int q    = lane >> 4;              // quad
    const int col  = lane & 15;
    const int relpx = (wv << 4) + col;       // 0..63 (pixel within tile for A)

    // ---- t-invariant staging slots: i = tid + it*256 -> (row r, scalar s)
    bool act[3], val[3];
    int  ofs[3], slot[3];
#pragma unroll
    for (int it = 0; it < 3; ++it) {
        int i  = tid + it * 256;
        act[it] = (i < NSTG);
        int r  = i / 132;
        int s  = i - r * 132;
        int y  = r0 - 1 + r;
        int px = (bx << 6) - 1 + (s >> 1);
        val[it] = act[it] && ((unsigned)y < (unsigned)HH) && ((unsigned)px < (unsigned)WW);
        ofs[it] = val[it] ? ((y * WW + px) * CINN + (s & 1)) : 0;
        slot[it] = r * LROW + s;
    }

    // ---- B fragments (weights), built once: k = q*8+j ; j<6: kx=j>>1, ci=j&1
    short8 Bh[4], Bl[4];
    float  biasv[4];
#pragma unroll
    for (int cg = 0; cg < 4; ++cg) {
        int hi_i[4] = {0, 0, 0, 0}, lo_i[4] = {0, 0, 0, 0};
#pragma unroll
        for (int j = 0; j < 6; ++j) {
            float w = 0.f;
            if (q < 3)
                w = w_conv[((q * 3 + (j >> 1)) * 2 + (j & 1)) * CHN + cg * 16 + col];
            unsigned hs = rne16(w);
            unsigned ls = rne16(w - b2f(hs));
            hi_i[j >> 1] |= (int)(hs << (16 * (j & 1)));
            lo_i[j >> 1] |= (int)(ls << (16 * (j & 1)));
        }
        int4v hv = {hi_i[0], hi_i[1], hi_i[2], hi_i[3]};
        int4v lv = {lo_i[0], lo_i[1], lo_i[2], lo_i[3]};
        Bh[cg] = __builtin_bit_cast(short8, hv);
        Bl[cg] = __builtin_bit_cast(short8, lv);
        biasv[cg] = b_conv[cg * 16 + col];
    }

    float V0[4][4], V1[4][4];                // membrane, rows r0 and r0+1
#pragma unroll
    for (int cg = 0; cg < 4; ++cg)
#pragma unroll
        for (int r = 0; r < 4; ++r) { V0[cg][r] = 0.f; V1[cg][r] = 0.f; }

    float ra[3], rb[3];                      // raw x[t+1], x[t]
    // preheader: issue loads for t = 0
    {
        const float* base0 = x + (size_t)(0 * BB + bz) * (HH * WW * CINN);
#pragma unroll
        for (int it = 0; it < 3; ++it)
            if (val[it]) {
                rb[it] = base0[ofs[it]];
                ra[it] = base0[ofs[it] + FRAME_ELEMS];
            }
    }

    for (int t = 0; t < TS; ++t) {
        // ---- pack raw -> LDS (hi16 | lo16) ; waits on loads issued last iter
        unsigned* buf = &lds2[t & 1][0];
#pragma unroll
        for (int it = 0; it < 3; ++it) {
            if (act[it]) {
                float d = val[it] ? (ra[it] - rb[it]) : 0.f;
                unsigned hs = rne16(d);
                unsigned ls = rne16(d - b2f(hs));
                buf[slot[it]] = hs | (ls << 16);
            }
        }
        __syncthreads();

        // ---- issue loads for t+1 (results consumed at top of next iter)
        if (t + 1 < TS) {
            const float* base0 = x + (size_t)((t + 1) * BB + bz) * (HH * WW * CINN);
#pragma unroll
            for (int it = 0; it < 3; ++it)
                if (val[it]) {
                    rb[it] = base0[ofs[it]];
                    ra[it] = base0[ofs[it] + FRAME_ELEMS];
                }
        }

        // ---- A fragments for both row-sets (6 contiguous dwords each)
        unsigned e0 = 0, e1 = 0, e2 = 0, e3 = 0, e4 = 0, e5 = 0;
        unsigned g0 = 0, g1 = 0, g2 = 0, g3 = 0, g4 = 0, g5 = 0;
        if (q < 3) {
            const unsigned* Lp = buf + q * LROW + relpx * 2;
            e0 = Lp[0]; e1 = Lp[1]; e2 = Lp[2]; e3 = Lp[3]; e4 = Lp[4]; e5 = Lp[5];
            const unsigned* Lq = Lp + LROW;
            g0 = Lq[0]; g1 = Lq[1]; g2 = Lq[2]; g3 = Lq[3]; g4 = Lq[4]; g5 = Lq[5];
        }
        int4v a0h = {(int)((e0 & 0xffffu) | (e1 << 16)),
                     (int)((e2 & 0xffffu) | (e3 << 16)),
                     (int)((e4 & 0xffffu) | (e5 << 16)), 0};
        int4v a0l = {(int)((e0 >> 16) | (e1 & 0xffff0000u)),
                     (int)((e2 >> 16) | (e3 & 0xffff0000u)),
                     (int)((e4 >> 16) | (e5 & 0xffff0000u)), 0};
        int4v a1h = {(int)((g0 & 0xffffu) | (g1 << 16)),
                     (int)((g2 & 0xffffu) | (g3 << 16)),
                     (int)((g4 & 0xffffu) | (g5 << 16)), 0};
        int4v a1l = {(int)((g0 >> 16) | (g1 & 0xffff0000u)),
                     (int)((g2 >> 16) | (g3 & 0xffff0000u)),
                     (int)((g4 >> 16) | (g5 & 0xffff0000u)), 0};
        short8 A0h = __builtin_bit_cast(short8, a0h);
        short8 A0l = __builtin_bit_cast(short8, a0l);
        short8 A1h = __builtin_bit_cast(short8, a1h);
        short8 A1l = __builtin_bit_cast(short8, a1l);

        // ---- conv (MFMA) + LIF + count
        int cnt0 = 0, cnt1 = 0, cnt2 = 0, cnt3 = 0;
#pragma unroll
        for (int cg = 0; cg < 4; ++cg) {
            float4v u0 = {biasv[cg], biasv[cg], biasv[cg], biasv[cg]};
            float4v u1 = u0;
            u0 = __builtin_amdgcn_mfma_f32_16x16x32_bf16(A0h, Bh[cg], u0, 0, 0, 0);
            u1 = __builtin_amdgcn_mfma_f32_16x16x32_bf16(A1h, Bh[cg], u1, 0, 0, 0);
            u0 = __builtin_amdgcn_mfma_f32_16x16x32_bf16(A0l, Bh[cg], u0, 0, 0, 0);
            u1 = __builtin_amdgcn_mfma_f32_16x16x32_bf16(A1l, Bh[cg], u1, 0, 0, 0);
            u0 = __builtin_amdgcn_mfma_f32_16x16x32_bf16(A0h, Bl[cg], u0, 0, 0, 0);
            u1 = __builtin_amdgcn_mfma_f32_16x16x32_bf16(A1h, Bl[cg], u1, 0, 0, 0);
            int c = 0;
#pragma unroll
            for (int r = 0; r < 4; ++r) {
                float v0 = fmaf(BETA, V0[cg][r], u0[r]);
                bool  s0 = v0 > THRV;
                c += s0 ? 1 : 0;
                V0[cg][r] = s0 ? (v0 - THRV) : v0;
                float v1 = fmaf(BETA, V1[cg][r], u1[r]);
                bool  s1 = v1 > THRV;
                c += s1 ? 1 : 0;
                V1[cg][r] = s1 ? (v1 - THRV) : v1;
            }
            c += __shfl_xor(c, 16);
            c += __shfl_xor(c, 32);
            if (cg == 0) cnt0 = c; else if (cg == 1) cnt1 = c;
            else if (cg == 2) cnt2 = c; else cnt3 = c;
        }
        int my = (q == 0) ? cnt0 : (q == 1) ? cnt1 : (q == 2) ? cnt2 : cnt3;
        // channel = q*16 + col = lane
        atomicAdd(&spikesum[(t * BB + bz) * CHN + lane], my);
    }
}

// ---------------------------------------------------------------------------
// head: logits[t][b][:] = (spikesum/16384) @ w_head + b_head ;
// readout += logits/TS (atomic) ; sr += local spikes / denom (atomic).
// out[0..159] and out[3200] must be zeroed before launch.
// ---------------------------------------------------------------------------
__global__ __launch_bounds__(64) void head_kernel(const int* __restrict__ spikesum,
                                                  const float* __restrict__ w_head,
                                                  const float* __restrict__ b_head,
                                                  float* __restrict__ out) {
    const int t = blockIdx.x, b = blockIdx.y, ch = threadIdx.x;
    const int sc = spikesum[(t * BB + b) * CHN + ch];
    const float s = (float)sc * (1.f / (HH * WW));
    float acc[NOUT];
#pragma unroll
    for (int o = 0; o < NOUT; ++o) acc[o] = s * w_head[ch * NOUT + o];
    int tot = sc;
#pragma unroll
    for (int off = 32; off > 0; off >>= 1) {
#pragma unroll
        for (int o = 0; o < NOUT; ++o) acc[o] += __shfl_down(acc[o], off);
        tot += __shfl_down(tot, off);
    }
    if (ch == 0) {
#pragma unroll
        for (int o = 0; o < NOUT; ++o) {
            float lg = acc[o] + b_head[o];
            out[BB * NOUT + (t * BB + b) * NOUT + o] = lg;
            atomicAdd(&out[b * NOUT + o], lg * (1.f / TS));
        }
        atomicAdd(&out[BB * NOUT + TS * BB * NOUT],
                  (float)tot * (1.f / ((float)TS * BB * HH * WW * CHN)));
    }
}

// ---------------------------------------------------------------------------
extern "C" void kernel_launch(void* const* d_in, const int* in_sizes, int n_in,
                              void* d_out, int out_size, void* d_ws, size_t ws_size,
                              hipStream_t stream) {
    (void)in_sizes; (void)n_in; (void)ws_size;
    const float* x      = (const float*)d_in[0];
    const float* w_conv = (const float*)d_in[1];
    const float* b_conv = (const float*)d_in[2];
    const float* w_head = (const float*)d_in[3];
    const float* b_head = (const float*)d_in[4];
    float* out      = (float*)d_out;
    int*   spikesum = (int*)d_ws;

    (void)hipMemsetAsync(d_ws, 0, SPIKESUM_BYTES, stream);
    (void)hipMemsetAsync(d_out, 0, (size_t)out_size * 4, stream);

    lif_main<<<dim3(2, HH / 2, BB), 256, 0, stream>>>(x, w_conv, b_conv, spikesum);
    head_kernel<<<dim3(TS, BB), 64, 0, stream>>>(spikesum, w_head, b_head, out);
}

// Round 7
// 201.938 us; speedup vs baseline: 10.2478x; 1.0303x over previous
//
#include <hip/hip_runtime.h>
#include <hip/hip_bf16.h>

// Problem constants
#define TT   20
#define TS   19          // T-1 steps
#define BB   16
#define HH   128
#define WW   128
#define CINN 2
#define CHN  64
#define NOUT 10
#define BETA 0.9f
#define THRV 1.0f

#define SPIKESUM_ELEMS (TS*BB*CHN)           // 19,456 ints
#define SPIKESUM_BYTES (SPIKESUM_ELEMS*4)    // 77,824 B

#define LROWD  68                             // dwords per plane row (66 + 2 pad)
#define NPAIR  264                            // 4 rows x 66 pixel-pairs per t

typedef __attribute__((ext_vector_type(8))) short short8;
typedef __attribute__((ext_vector_type(4))) float float4v;
typedef __attribute__((ext_vector_type(4))) int   int4v;

// round-to-nearest-even fp32 -> bf16 bits
__device__ __forceinline__ unsigned rne16(float f) {
    unsigned u = __float_as_uint(f);
    return (u + 0x7fffu + ((u >> 16) & 1u)) >> 16;
}
__device__ __forceinline__ float b2f(unsigned us) {
    return __uint_as_float(us << 16);
}

// ---------------------------------------------------------------------------
// Fused flow-diff + 3x3 conv (bf16-split MFMA) + LIF scan + spike count.
//
// Block = 2 rows x 64 px, all 64 channels; wave = 16 px x 2 row-sets.
// Pipelined t-loop, double-buffered two-plane LDS (hi bf16 / lo bf16,
// packed pairs), ONE barrier per t. x slices are register-carried:
// rb = ra rotation means only x[t+1] is loaded each step, one float2
// (both ci of one pixel) per thread per step.
// A-fragments: ds_read_b64 + ds_read_b32 per plane (no unpack bitops).
// k-remap: quad = ky, j = kx*2+ci (j<6); k=24 is a constant-1.0 tap whose
// B value is the bias (hi+lo split) — bias costs zero extra VALU.
// u = Ah*Bh + Al*Bh + Ah*Bl (drops Alo*Blo ~ 2^-16 relative).
// C/D layout: row(pixel) = q*4+reg, col(channel-in-group) = lane&15.
// ---------------------------------------------------------------------------
__global__ __launch_bounds__(256, 4) void lif_main(const float* __restrict__ x,
                                                   const float* __restrict__ w_conv,
                                                   const float* __restrict__ b_conv,
                                                   int* __restrict__ spikesum) {
    __shared__ unsigned lds2[2][2][4 * LROWD];   // [buf][plane][row*68+dw] = 4352 B

    const float2* xp2 = (const float2*)x;        // pixel-granular (ci pair)
    const int FRAME2  = BB * HH * WW;            // float2s per time slice

    const int tid  = threadIdx.x;
    const int lane = tid & 63;
    const int wv   = __builtin_amdgcn_readfirstlane(tid >> 6); // uniform 0..3
    const int bx   = blockIdx.x;                 // 0..1 : pixel half
    const int r0   = blockIdx.y << 1;            // first of 2 output rows
    const int bz   = blockIdx.z;                 // batch
    const int q    = lane >> 4;                  // quad
    const int col  = lane & 15;
    const int relpx = (wv << 4) + col;           // 0..63 pixel within tile

    // ---- t-invariant staging slots (pair = one pixel, both ci)
    // slot0: pair tid ; slot1: pair 256+tid (only tid<8)
    const int  pr0 = tid;
    const int  ra0r = pr0 / 66, ra0d = pr0 - ra0r * 66;
    const int  y0s  = r0 - 1 + ra0r;
    const int  px0s = (bx << 6) - 1 + ra0d;
    const bool val0 = ((unsigned)y0s < (unsigned)HH) && ((unsigned)px0s < (unsigned)WW);
    const int  off0 = val0 ? (y0s * WW + px0s) : 0;
    const int  ls0  = ra0r * LROWD + ra0d;

    const bool act1 = (tid < NPAIR - 256);
    const int  pr1 = 256 + tid;
    const int  ra1r = pr1 / 66, ra1d = pr1 - ra1r * 66;
    const int  y1s  = r0 - 1 + ra1r;
    const int  px1s = (bx << 6) - 1 + ra1d;
    const bool val1 = act1 && ((unsigned)y1s < (unsigned)HH) && ((unsigned)px1s < (unsigned)WW);
    const int  off1 = val1 ? (y1s * WW + px1s) : 0;
    const int  ls1  = ra1r * LROWD + ra1d;

    // ---- B fragments: k = q*8+j ; q<3,j<6: weights ; q==3,j==0: bias tap
    short8 Bh[4], Bl[4];
#pragma unroll
    for (int cg = 0; cg < 4; ++cg) {
        int hi_i[4] = {0, 0, 0, 0}, lo_i[4] = {0, 0, 0, 0};
        if (q < 3) {
#pragma unroll
            for (int j = 0; j < 6; ++j) {
                float w = w_conv[((q * 3 + (j >> 1)) * 2 + (j & 1)) * CHN + cg * 16 + col];
                unsigned hs = rne16(w);
                unsigned ls = rne16(w - b2f(hs));
                hi_i[j >> 1] |= (int)(hs << (16 * (j & 1)));
                lo_i[j >> 1] |= (int)(ls << (16 * (j & 1)));
            }
        } else {
            float bb = b_conv[cg * 16 + col];
            unsigned hs = rne16(bb);
            unsigned ls = rne16(bb - b2f(hs));
            hi_i[0] = (int)hs;
            lo_i[0] = (int)ls;
        }
        int4v hv = {hi_i[0], hi_i[1], hi_i[2], hi_i[3]};
        int4v lv = {lo_i[0], lo_i[1], lo_i[2], lo_i[3]};
        Bh[cg] = __builtin_bit_cast(short8, hv);
        Bl[cg] = __builtin_bit_cast(short8, lv);
    }
    const unsigned acst = (q == 3) ? 0x3f80u : 0u;   // A k=24 tap = 1.0 (bf16)

    float V0[4][4], V1[4][4];                    // membrane, rows r0, r0+1
#pragma unroll
    for (int cg = 0; cg < 4; ++cg)
#pragma unroll
        for (int r = 0; r < 4; ++r) { V0[cg][r] = 0.f; V1[cg][r] = 0.f; }

    // ---- preheader: rb = x[0], ra = x[1]
    float2 ra_0 = {0.f, 0.f}, rb_0 = {0.f, 0.f};
    float2 ra_1 = {0.f, 0.f}, rb_1 = {0.f, 0.f};
    {
        const int s2a = bz * HH * WW;             // slice 0 base (float2)
        if (val0) { rb_0 = xp2[s2a + off0]; ra_0 = xp2[s2a + FRAME2 + off0]; }
        if (val1) { rb_1 = xp2[s2a + off1]; ra_1 = xp2[s2a + FRAME2 + off1]; }
    }

    for (int t = 0; t < TS; ++t) {
        // ---- pack flow = ra - rb into two bf16 planes
        unsigned* hiP = &lds2[t & 1][0][0];
        unsigned* loP = &lds2[t & 1][1][0];
        {
            float d0 = val0 ? (ra_0.x - rb_0.x) : 0.f;
            float d1 = val0 ? (ra_0.y - rb_0.y) : 0.f;
            unsigned h0 = rne16(d0), h1 = rne16(d1);
            unsigned l0 = rne16(d0 - b2f(h0)), l1 = rne16(d1 - b2f(h1));
            hiP[ls0] = h0 | (h1 << 16);
            loP[ls0] = l0 | (l1 << 16);
        }
        if (act1) {
            float d0 = val1 ? (ra_1.x - rb_1.x) : 0.f;
            float d1 = val1 ? (ra_1.y - rb_1.y) : 0.f;
            unsigned h0 = rne16(d0), h1 = rne16(d1);
            unsigned l0 = rne16(d0 - b2f(h0)), l1 = rne16(d1 - b2f(h1));
            hiP[ls1] = h0 | (h1 << 16);
            loP[ls1] = l0 | (l1 << 16);
        }
        __syncthreads();

        // ---- rotate and issue loads for t+1 (x slice t+2)
        if (t + 1 < TS) {
            const int s2n = ((t + 2) * BB + bz) * (HH * WW);
            rb_0 = ra_0; rb_1 = ra_1;
            if (val0) ra_0 = xp2[s2n + off0];
            if (val1) ra_1 = xp2[s2n + off1];
        }

        // ---- A fragments: 3 dwords per plane per row-set (q<3)
        unsigned h0 = 0, h1 = 0, h2 = 0, l0 = 0, l1 = 0, l2 = 0;
        unsigned h3 = 0, h4 = 0, h5 = 0, l3 = 0, l4 = 0, l5 = 0;
        if (q < 3) {
            const unsigned* hp = hiP + q * LROWD + relpx;
            const unsigned* lp = loP + q * LROWD + relpx;
            h0 = hp[0]; h1 = hp[1]; h2 = hp[2];
            l0 = lp[0]; l1 = lp[1]; l2 = lp[2];
            h3 = hp[LROWD]; h4 = hp[LROWD + 1]; h5 = hp[LROWD + 2];
            l3 = lp[LROWD]; l4 = lp[LROWD + 1]; l5 = lp[LROWD + 2];
        }
        int4v a0h = {(int)h0, (int)h1, (int)h2, (int)acst};
        int4v a0l = {(int)l0, (int)l1, (int)l2, 0};
        int4v a1h = {(int)h3, (int)h4, (int)h5, (int)acst};
        int4v a1l = {(int)l3, (int)l4, (int)l5, 0};
        short8 A0h = __builtin_bit_cast(short8, a0h);
        short8 A0l = __builtin_bit_cast(short8, a0l);
        short8 A1h = __builtin_bit_cast(short8, a1h);
        short8 A1l = __builtin_bit_cast(short8, a1l);

        // ---- conv (MFMA) + LIF + count
        int cnt0 = 0, cnt1 = 0, cnt2 = 0, cnt3 = 0;
#pragma unroll
        for (int cg = 0; cg < 4; ++cg) {
            float4v u0 = {0.f, 0.f, 0.f, 0.f};
            float4v u1 = {0.f, 0.f, 0.f, 0.f};
            u0 = __builtin_amdgcn_mfma_f32_16x16x32_bf16(A0h, Bh[cg], u0, 0, 0, 0);
            u1 = __builtin_amdgcn_mfma_f32_16x16x32_bf16(A1h, Bh[cg], u1, 0, 0, 0);
            u0 = __builtin_amdgcn_mfma_f32_16x16x32_bf16(A0l, Bh[cg], u0, 0, 0, 0);
            u1 = __builtin_amdgcn_mfma_f32_16x16x32_bf16(A1l, Bh[cg], u1, 0, 0, 0);
            u0 = __builtin_amdgcn_mfma_f32_16x16x32_bf16(A0h, Bl[cg], u0, 0, 0, 0);
            u1 = __builtin_amdgcn_mfma_f32_16x16x32_bf16(A1h, Bl[cg], u1, 0, 0, 0);
            int c = 0;
#pragma unroll
            for (int r = 0; r < 4; ++r) {
                float v0 = fmaf(BETA, V0[cg][r], u0[r]);
                bool  s0 = v0 > THRV;
                c += s0 ? 1 : 0;
                V0[cg][r] = s0 ? (v0 - THRV) : v0;
                float v1 = fmaf(BETA, V1[cg][r], u1[r]);
                bool  s1 = v1 > THRV;
                c += s1 ? 1 : 0;
                V1[cg][r] = s1 ? (v1 - THRV) : v1;
            }
            c += __shfl_xor(c, 16);
            c += __shfl_xor(c, 32);
            if (cg == 0) cnt0 = c; else if (cg == 1) cnt1 = c;
            else if (cg == 2) cnt2 = c; else cnt3 = c;
        }
        int my = (q == 0) ? cnt0 : (q == 1) ? cnt1 : (q == 2) ? cnt2 : cnt3;
        // channel = q*16 + col = lane
        atomicAdd(&spikesum[(t * BB + bz) * CHN + lane], my);
    }
}

// ---------------------------------------------------------------------------
// head: logits[t][b][:] = (spikesum/16384) @ w_head + b_head ;
// readout += logits/TS (atomic) ; sr += local spikes / denom (atomic).
// out must be zeroed before launch.
// ---------------------------------------------------------------------------
__global__ __launch_bounds__(64) void head_kernel(const int* __restrict__ spikesum,
                                                  const float* __restrict__ w_head,
                                                  const float* __restrict__ b_head,
                                                  float* __restrict__ out) {
    const int t = blockIdx.x, b = blockIdx.y, ch = threadIdx.x;
    const int sc = spikesum[(t * BB + b) * CHN + ch];
    const float s = (float)sc * (1.f / (HH * WW));
    float acc[NOUT];
#pragma unroll
    for (int o = 0; o < NOUT; ++o) acc[o] = s * w_head[ch * NOUT + o];
    int tot = sc;
#pragma unroll
    for (int off = 32; off > 0; off >>= 1) {
#pragma unroll
        for (int o = 0; o < NOUT; ++o) acc[o] += __shfl_down(acc[o], off);
        tot += __shfl_down(tot, off);
    }
    if (ch == 0) {
#pragma unroll
        for (int o = 0; o < NOUT; ++o) {
            float lg = acc[o] + b_head[o];
            out[BB * NOUT + (t * BB + b) * NOUT + o] = lg;
            atomicAdd(&out[b * NOUT + o], lg * (1.f / TS));
        }
        atomicAdd(&out[BB * NOUT + TS * BB * NOUT],
                  (float)tot * (1.f / ((float)TS * BB * HH * WW * CHN)));
    }
}

// ---------------------------------------------------------------------------
extern "C" void kernel_launch(void* const* d_in, const int* in_sizes, int n_in,
                              void* d_out, int out_size, void* d_ws, size_t ws_size,
                              hipStream_t stream) {
    (void)in_sizes; (void)n_in; (void)ws_size;
    const float* x      = (const float*)d_in[0];
    const float* w_conv = (const float*)d_in[1];
    const float* b_conv = (const float*)d_in[2];
    const float* w_head = (const float*)d_in[3];
    const float* b_head = (const float*)d_in[4];
    float* out      = (float*)d_out;
    int*   spikesum = (int*)d_ws;

    (void)hipMemsetAsync(d_ws, 0, SPIKESUM_BYTES, stream);
    (void)hipMemsetAsync(d_out, 0, (size_t)out_size * 4, stream);

    lif_main<<<dim3(2, HH / 2, BB), 256, 0, stream>>>(x, w_conv, b_conv, spikesum);
    head_kernel<<<dim3(TS, BB), 64, 0, stream>>>(spikesum, w_head, b_head, out);
}